// Round 3
// baseline (956.593 us; speedup 1.0000x reference)
//
#include <hip/hip_runtime.h>
#include <hip/hip_bf16.h>
#include <math.h>

// TENLayer: LN1 -> eigen-projection -> diagonal complex scan -> folded readout GEMM
//           -> +residual -> LN2 -> MLP(gelu exact) -> +residual.  fp16 MFMA GEMMs.
//
// Shapes: B=4, T=4096 (BT=16384 rows), D=1024, K=64 (128 cat), MLP=4096.
// Workspace budget: ~81 MB (act chunked x4; y lives in d_out; xn/yn shared).

#define D 1024
#define TSEQ 4096
#define BT_ROWS 16384
#define CHUNK 4096            // MLP row-chunk (4 chunks)

typedef __attribute__((ext_vector_type(8))) _Float16 f16x8;
typedef __attribute__((ext_vector_type(4))) _Float16 f16x4;
typedef __attribute__((ext_vector_type(4))) float f32x4;

__device__ inline _Float16 f2h(float f) { return (_Float16)f; }

// global -> LDS direct (16B/lane). LDS dest = wave-uniform base + lane*16, which
// our linear thread->offset mapping (offset = tid*16) satisfies.
#define GLL16(g, l)                                                              \
  __builtin_amdgcn_global_load_lds(                                              \
      (const __attribute__((address_space(1))) void*)(g),                        \
      (__attribute__((address_space(3))) void*)(l), 16, 0, 0)

// ---------------------------------------------------------------------------
// GEMM: C[M][N] = A[M][Kd] @ Bt[N][Kd]^T   (NT), fp16 in, fp32 accum.
// 128x128 block tile, 4 waves in 2x2, each wave 4x4 frags of 16x16x32 MFMA.
// EPI: 0 = plain fp32 store; 1 = resid + acc + bias -> fp32 (resid may == Cf);
//      2 = gelu(acc+bias) -> fp16
// ---------------------------------------------------------------------------
template <int EPI>
__global__ __launch_bounds__(256) void gemm_bt(
    const _Float16* __restrict__ A, const _Float16* __restrict__ Bt,
    int N, int Kd,
    float* __restrict__ Cf, _Float16* __restrict__ Ch,
    const float* __restrict__ bias, const float* __restrict__ resid)
{
  __shared__ __align__(16) _Float16 lA[128 * 32];
  __shared__ __align__(16) _Float16 lB[128 * 32];
  const int t = threadIdx.x;
  const int wid = t >> 6, lane = t & 63;
  const int brow = blockIdx.y << 7, bcol = blockIdx.x << 7;
  const int wr = wid >> 1, wc = wid & 1;

  f32x4 acc[4][4] = {};

  // staging map: thread t covers row r0 = t/4 (+64), k-group (t&3)*8 -> LDS byte off 16*t
  const int r0 = t >> 2;
  const int kg = (t & 3) << 3;
  const _Float16* gA0 = A + (size_t)(brow + r0) * Kd + kg;
  const _Float16* gB0 = Bt + (size_t)(bcol + r0) * Kd + kg;
  const size_t rowskip = (size_t)64 * Kd;
  _Float16* lA0 = &lA[r0 * 32 + kg];
  _Float16* lB0 = &lB[r0 * 32 + kg];

  const int rr = lane & 15;          // fragment row/col within 16
  const int ko = (lane >> 4) << 3;   // k offset: 8 contiguous per lane-group

  for (int k0 = 0; k0 < Kd; k0 += 32) {
    __syncthreads();                  // previous iteration's LDS reads done
    GLL16(gA0 + k0, lA0);
    GLL16(gA0 + k0 + rowskip, lA0 + 64 * 32);
    GLL16(gB0 + k0, lB0);
    GLL16(gB0 + k0 + rowskip, lB0 + 64 * 32);
    __syncthreads();                  // vmcnt(0) drained before barrier -> tiles ready

    f16x8 af[4], bfr[4];
#pragma unroll
    for (int m = 0; m < 4; ++m)
      af[m] = *(const f16x8*)&lA[(wr * 64 + m * 16 + rr) * 32 + ko];
#pragma unroll
    for (int n = 0; n < 4; ++n)
      bfr[n] = *(const f16x8*)&lB[(wc * 64 + n * 16 + rr) * 32 + ko];
#pragma unroll
    for (int m = 0; m < 4; ++m)
#pragma unroll
      for (int n = 0; n < 4; ++n)
        acc[m][n] = __builtin_amdgcn_mfma_f32_16x16x32_f16(af[m], bfr[n], acc[m][n], 0, 0, 0);
  }

  // C/D layout (HW-verified): col = lane&15, row = (lane>>4)*4 + reg
  const int cc = lane & 15;
  const int rb = (lane >> 4) << 2;
#pragma unroll
  for (int m = 0; m < 4; ++m) {
#pragma unroll
    for (int n = 0; n < 4; ++n) {
      const int gr = brow + wr * 64 + m * 16 + rb;
      const int gc = bcol + wc * 64 + n * 16 + cc;
#pragma unroll
      for (int q = 0; q < 4; ++q) {
        const size_t idx = (size_t)(gr + q) * N + gc;
        const float v = acc[m][n][q];
        if constexpr (EPI == 0) {
          Cf[idx] = v;
        } else if constexpr (EPI == 1) {
          Cf[idx] = resid[idx] + v + bias[gc];
        } else {
          const float u = v + bias[gc];
          Ch[idx] = f2h(0.5f * u * (1.0f + erff(u * 0.70710678118654752f)));
        }
      }
    }
  }
}

// ---------------------------------------------------------------------------
// LayerNorm (fp32 stats) -> fp16 out. One block per row.
// ---------------------------------------------------------------------------
__global__ __launch_bounds__(256) void ln_f16(
    const float* __restrict__ x, const float* __restrict__ g,
    const float* __restrict__ b, _Float16* __restrict__ out)
{
  const int row = blockIdx.x;
  const int t = threadIdx.x;
  const size_t base = (size_t)row * D + t * 4;
  const float4 v = *(const float4*)(x + base);
  float s = v.x + v.y + v.z + v.w;
  float q = v.x * v.x + v.y * v.y + v.z * v.z + v.w * v.w;
#pragma unroll
  for (int off = 32; off > 0; off >>= 1) {
    s += __shfl_xor(s, off);
    q += __shfl_xor(q, off);
  }
  __shared__ float rs[4], rq[4];
  const int wid = t >> 6, lane = t & 63;
  if (lane == 0) { rs[wid] = s; rq[wid] = q; }
  __syncthreads();
  s = rs[0] + rs[1] + rs[2] + rs[3];
  q = rq[0] + rq[1] + rq[2] + rq[3];
  const float mean = s * (1.0f / D);
  const float var = q * (1.0f / D) - mean * mean;
  const float rstd = rsqrtf(var + 1e-5f);
  const float4 gg = *(const float4*)(g + t * 4);
  const float4 bb = *(const float4*)(b + t * 4);
  f16x4 o;
  o[0] = f2h((v.x - mean) * rstd * gg.x + bb.x);
  o[1] = f2h((v.y - mean) * rstd * gg.y + bb.y);
  o[2] = f2h((v.z - mean) * rstd * gg.z + bb.z);
  o[3] = f2h((v.w - mean) * rstd * gg.w + bb.w);
  *(f16x4*)(out + base) = o;
}

// ---------------------------------------------------------------------------
// Diagonal complex scan, chunked. |lambda| < 0.5 -> 64-step warm-up is exact
// to fp32 (0.5^64 ~ 5e-20). Thread = k, block = (chunk, batch).
// ---------------------------------------------------------------------------
__global__ __launch_bounds__(64) void scan_k(
    const float* __restrict__ beta, const float* __restrict__ state,
    const float* __restrict__ alpha, const float* __restrict__ omega,
    _Float16* __restrict__ c_cat, float* __restrict__ fs)
{
  const int k = threadIdx.x;
  const int chunk = blockIdx.x;   // 0..63 (64 steps each)
  const int b = blockIdx.y;       // 0..3
  const float a = alpha[k];
  const float mag = 1.0f / (1.0f + expf(-a));
  const float om = omega[k];
  const float lr = mag * cosf(om);
  const float li = mag * sinf(om);
  const int t0 = chunk * 64;
  float cr, ci;
  int t;
  if (chunk == 0) {
    cr = state[(b * 64 + k) * 2 + 0];
    ci = state[(b * 64 + k) * 2 + 1];
    t = 0;
  } else {
    cr = 0.0f; ci = 0.0f;
    t = t0 - 64;                  // warm-up window
  }
  for (; t < t0 + 64; ++t) {
    const float* bp = beta + ((size_t)(b * TSEQ + t) << 7);
    const float br = bp[k];
    const float bi = bp[64 + k];
    const float ncr = lr * cr - li * ci + br;
    const float nci = lr * ci + li * cr + bi;
    cr = ncr; ci = nci;
    if (t >= t0) {
      _Float16* cp = c_cat + ((size_t)(b * TSEQ + t) << 7);
      cp[k] = f2h(cr);
      cp[64 + k] = f2h(ci);
    }
  }
  if (chunk == 63) {
    fs[(b * 64 + k) * 2 + 0] = cr;
    fs[(b * 64 + k) * 2 + 1] = ci;
  }
}

// ---------------------------------------------------------------------------
// transpose + fp32->fp16:  dst[C][R] = src[R][C]
// ---------------------------------------------------------------------------
__global__ void tr_cvt(const float* __restrict__ src, _Float16* __restrict__ dst,
                       int R, int C)
{
  __shared__ float tile[32][33];
  const int bx = blockIdx.x * 32;  // col base in src
  const int by = blockIdx.y * 32;  // row base in src
  const int tx = threadIdx.x, ty = threadIdx.y;
#pragma unroll
  for (int i = 0; i < 32; i += 8)
    tile[ty + i][tx] = src[(size_t)(by + ty + i) * C + bx + tx];
  __syncthreads();
#pragma unroll
  for (int i = 0; i < 32; i += 8)
    dst[(size_t)(bx + ty + i) * R + by + tx] = f2h(tile[tx][ty + i]);
}

// Ecat[128][1024] = [eigvec_real ; -eigvec_imag]  (fp16)
__global__ void build_Ecat(const float* __restrict__ er, const float* __restrict__ ei,
                           _Float16* __restrict__ E)
{
  const int i = blockIdx.x * 256 + threadIdx.x;  // 0..131071
  const float v = (i < 65536) ? er[i] : -ei[i - 65536];
  E[i] = f2h(v);
}

// G[128][1024] = [R^T @ er ; -(R^T @ ei)],  R = I + eps*M  => R^T[j][k] = d_jk + eps*M[k][j]
__global__ void build_G(const float* __restrict__ er, const float* __restrict__ ei,
                        const float* __restrict__ Mm, const float* __restrict__ epsp,
                        float* __restrict__ G)
{
  const int j = blockIdx.y;                       // 0..127
  const int d = blockIdx.x * 256 + threadIdx.x;   // 0..1023
  const float* e = (j < 64) ? er : ei;
  const int jj = j & 63;
  const float eps = epsp[0];
  float acc = 0.0f;
  for (int k = 0; k < 64; ++k)
    acc += Mm[k * 64 + jj] * e[(size_t)k * D + d];
  const float v = e[(size_t)jj * D + d] + eps * acc;
  G[(size_t)j * D + d] = (j < 64) ? v : -v;
}

// WhoT[1024][128] (fp16) = (G @ out_w)^T  -- folds eigen readout + out_w into one 128xD matrix
__global__ void build_WhoT(const float* __restrict__ G, const float* __restrict__ ow,
                           _Float16* __restrict__ WhoT)
{
  const int j = blockIdx.y;                       // 0..127
  const int d = blockIdx.x * 256 + threadIdx.x;   // 0..1023
  float acc = 0.0f;
  for (int k = 0; k < D; ++k)
    acc += G[(size_t)j * D + k] * ow[(size_t)k * D + d];
  WhoT[(size_t)d * 128 + j] = f2h(acc);
}

// ---------------------------------------------------------------------------
extern "C" void kernel_launch(void* const* d_in, const int* in_sizes, int n_in,
                              void* d_out, int out_size, void* d_ws, size_t ws_size,
                              hipStream_t stream) {
  const float* x     = (const float*)d_in[0];
  const float* state = (const float*)d_in[1];
  const float* er    = (const float*)d_in[2];
  const float* ei    = (const float*)d_in[3];
  const float* alpha = (const float*)d_in[4];
  const float* omega = (const float*)d_in[5];
  const float* epsv  = (const float*)d_in[6];
  const float* Mm    = (const float*)d_in[7];
  const float* out_w = (const float*)d_in[8];
  const float* out_b = (const float*)d_in[9];
  const float* w1    = (const float*)d_in[10];
  const float* b1    = (const float*)d_in[11];
  const float* w2    = (const float*)d_in[12];
  const float* b2    = (const float*)d_in[13];
  const float* g1    = (const float*)d_in[14];
  const float* be1   = (const float*)d_in[15];
  const float* g2    = (const float*)d_in[16];
  const float* be2   = (const float*)d_in[17];

  float* out = (float*)d_out;
  float* fs  = out + (size_t)BT_ROWS * D;   // final_state after the (B,T,D) block
  float* y   = out;                          // y lives in d_out (overwritten in-place at the end)

  // ---- workspace layout: ~81 MB total ----
  char* w = (char*)d_ws;
  _Float16* act  = (_Float16*)(w);                 // 32 MB  (CHUNK x 4096 fp16) -- stage 3
  float*    beta = (float*)   (w);                 //  8 MB  (aliases act; dead before stage 3)
  _Float16* ccat = (_Float16*)(w + 8388608u);      //  4 MB  (aliases act; dead before stage 3)
  _Float16* xnyn = (_Float16*)(w + 33554432u);     // 32 MB  (xn stage 1, yn stages 2-3)
  _Float16* w1T  = (_Float16*)(w + 67108864u);     //  8 MB
  _Float16* w2T  = (_Float16*)(w + 75497472u);     //  8 MB
  float*    G    = (float*)   (w + 83886080u);     // 512 KB
  _Float16* WhoT = (_Float16*)(w + 84410368u);     // 256 KB
  _Float16* Ecat = (_Float16*)(w + 84672512u);     // 256 KB   (end ~84.9 MB)

  // stage 0: small precomputes + weight transposes (independent)
  build_Ecat<<<512, 256, 0, stream>>>(er, ei, Ecat);
  build_G<<<dim3(4, 128), 256, 0, stream>>>(er, ei, Mm, epsv, G);
  build_WhoT<<<dim3(4, 128), 256, 0, stream>>>(G, out_w, WhoT);
  tr_cvt<<<dim3(128, 32), dim3(32, 8), 0, stream>>>(w1, w1T, 1024, 4096);
  tr_cvt<<<dim3(32, 128), dim3(32, 8), 0, stream>>>(w2, w2T, 4096, 1024);

  // stage 1: LN1 -> beta -> scan
  ln_f16<<<BT_ROWS, 256, 0, stream>>>(x, g1, be1, xnyn);
  gemm_bt<0><<<dim3(1, 128), 256, 0, stream>>>(xnyn, Ecat, 128, 1024, beta, nullptr, nullptr, nullptr);
  scan_k<<<dim3(64, 4), 64, 0, stream>>>(beta, state, alpha, omega, ccat, fs);

  // stage 2: y = x + ccat @ Who + out_b  (into d_out); LN2 -> yn
  gemm_bt<1><<<dim3(8, 128), 256, 0, stream>>>(ccat, WhoT, 1024, 128, y, nullptr, out_b, x);
  ln_f16<<<BT_ROWS, 256, 0, stream>>>(y, g2, be2, xnyn);

  // stage 3: MLP, row-chunked x4 (act = 32 MB per chunk); final residual in-place on d_out
  for (int c = 0; c < BT_ROWS / CHUNK; ++c) {
    const size_t ro = (size_t)c * CHUNK;
    gemm_bt<2><<<dim3(32, CHUNK / 128), 256, 0, stream>>>(
        xnyn + ro * D, w1T, 4096, 1024, nullptr, act, b1, nullptr);
    gemm_bt<1><<<dim3(8, CHUNK / 128), 256, 0, stream>>>(
        act, w2T, 1024, 4096, out + ro * D, nullptr, b2, y + ro * D);
  }
}

// Round 4
// 710.865 us; speedup vs baseline: 1.3457x; 1.3457x over previous
//
#include <hip/hip_runtime.h>
#include <hip/hip_bf16.h>
#include <math.h>

// TENLayer: LN1 -> eigen-projection -> diagonal complex scan -> folded readout GEMM
//           -> +residual -> LN2 -> MLP(gelu exact) -> +residual.  fp16 MFMA GEMMs.
//
// Round 4: GEMM rewritten as 2-phase double-buffered pipeline (counted vmcnt +
// raw s_barrier, never drain-to-0), BK=64, XOR-swizzled LDS (both-sides with
// pre-swizzled global source), and BN template (128/64) for grid shaping.

#define D 1024
#define TSEQ 4096
#define BT_ROWS 16384
#define CHUNK 4096            // MLP row-chunk (4 chunks)

typedef __attribute__((ext_vector_type(8))) _Float16 f16x8;
typedef __attribute__((ext_vector_type(4))) _Float16 f16x4;
typedef __attribute__((ext_vector_type(4))) float f32x4;

__device__ inline _Float16 f2h(float f) { return (_Float16)f; }

// global -> LDS direct (16B/lane). LDS dest = wave-uniform base + lane*16; our
// mapping (lds half-offset = t*8 within each 4KB call-chunk) satisfies this.
#define GLL16(g, l)                                                              \
  __builtin_amdgcn_global_load_lds(                                              \
      (const __attribute__((address_space(1))) void*)(g),                        \
      (__attribute__((address_space(3))) void*)(l), 16, 0, 0)

// ---------------------------------------------------------------------------
// GEMM: C[M][N] = A[M][Kd] @ Bt[N][Kd]^T   (NT), fp16 in, fp32 accum.
// Block tile 128 x BN (BN = NFRAG*32), BK=64, 4 waves in 2x2.
// LDS layout: logical [row][kblk16B] stored at phys kblk = logical ^ (row&7)
// (XOR swizzle). global_load_lds writes linearly; the SOURCE address is
// pre-swizzled per-lane (rule #21: both-sides-or-neither), coalescing kept
// (permutation stays inside each 128-B segment).
// Pipeline: stage(next) -> vmcnt(L) -> s_barrier -> compute(cur) ->
//           lgkmcnt(0) -> s_barrier.  Counted vmcnt keeps next tile's loads
//           in flight across the barrier (T3/T4 minimum 2-phase).
// EPI: 0 = fp32 store; 1 = resid+acc+bias -> fp32 (resid may alias Cf);
//      2 = gelu(acc+bias) -> fp16
// ---------------------------------------------------------------------------
template <int EPI, int NFRAG>
__global__ __launch_bounds__(256) void gemm_bt(
    const _Float16* __restrict__ A, const _Float16* __restrict__ Bt,
    int N, int Kd,
    float* __restrict__ Cf, _Float16* __restrict__ Ch,
    const float* __restrict__ bias, const float* __restrict__ resid)
{
  constexpr int BN = NFRAG * 32;
  constexpr int BCALLS = BN / 32;        // stage calls for B (A is 4)
  constexpr int ASZ = 128 * 64;          // halfs per buffer (A)
  constexpr int BSZ = BN * 64;           // halfs per buffer (B)
  __shared__ __align__(16) _Float16 lds[2][ASZ + BSZ];

  const int t = threadIdx.x;
  const int wid = t >> 6, lane = t & 63;
  const int brow = blockIdx.y << 7;
  const int bcol = blockIdx.x * BN;
  const int wr = wid >> 1, wc = wid & 1;

  f32x4 acc[4][NFRAG] = {};

  // staging map: call i covers row i*32 + (t>>3); lane's 16B goes to LDS half
  // offset i*2048 + t*8 (linear). Source column block is pre-swizzled:
  // logical kb = (t&7) ^ (row&7), so phys slot (t&7) holds what the swizzled
  // reader expects.
  const int srow = t >> 3;
  const int skb = (((t & 7) ^ (srow & 7)) << 3);  // halfs
  const _Float16* gA = A + (size_t)(brow + srow) * Kd + skb;
  const _Float16* gB = Bt + (size_t)(bcol + srow) * Kd + skb;

  const int rr = lane & 15, g = lane >> 4;

  auto stage = [&](int buf, int k0) {
    _Float16* dst = &lds[buf][0];
#pragma unroll
    for (int i = 0; i < 4; ++i)
      GLL16(gA + (size_t)(i * 32) * Kd + k0, dst + i * 2048 + t * 8);
#pragma unroll
    for (int i = 0; i < BCALLS; ++i)
      GLL16(gB + (size_t)(i * 32) * Kd + k0, dst + ASZ + i * 2048 + t * 8);
  };

  const int nsteps = Kd >> 6;
  stage(0, 0);
  int cur = 0;
  for (int s = 0; s < nsteps; ++s) {
    if (s + 1 < nsteps) {
      stage(cur ^ 1, (s + 1) << 6);
      // wait only for cur's 4+BCALLS loads; next tile's stay in flight
      if constexpr (NFRAG == 4) asm volatile("s_waitcnt vmcnt(8)" ::: "memory");
      else                      asm volatile("s_waitcnt vmcnt(6)" ::: "memory");
    } else {
      asm volatile("s_waitcnt vmcnt(0)" ::: "memory");
    }
    __builtin_amdgcn_s_barrier();        // cur fully staged (each wave waited its own)

    const _Float16* la = &lds[cur][0];
    const _Float16* lb = la + ASZ;
#pragma unroll
    for (int kk = 0; kk < 2; ++kk) {
      f16x8 af[4], bfr[NFRAG];
#pragma unroll
      for (int m = 0; m < 4; ++m) {
        const int row = wr * 64 + m * 16 + rr;
        af[m] = *(const f16x8*)&la[row * 64 + (((g + 4 * kk) ^ (row & 7)) << 3)];
      }
#pragma unroll
      for (int n = 0; n < NFRAG; ++n) {
        const int row = wc * (BN / 2) + n * 16 + rr;
        bfr[n] = *(const f16x8*)&lb[row * 64 + (((g + 4 * kk) ^ (row & 7)) << 3)];
      }
#pragma unroll
      for (int m = 0; m < 4; ++m)
#pragma unroll
        for (int n = 0; n < NFRAG; ++n)
          acc[m][n] = __builtin_amdgcn_mfma_f32_16x16x32_f16(af[m], bfr[n], acc[m][n], 0, 0, 0);
    }
    asm volatile("s_waitcnt lgkmcnt(0)" ::: "memory");  // done reading cur
    __builtin_amdgcn_s_barrier();        // safe to overwrite cur next iter
    cur ^= 1;
  }

  // C/D layout (HW-verified): col = lane&15, row = (lane>>4)*4 + reg
  const int cc = lane & 15;
  const int rb = (lane >> 4) << 2;
#pragma unroll
  for (int m = 0; m < 4; ++m) {
#pragma unroll
    for (int n = 0; n < NFRAG; ++n) {
      const int gr = brow + wr * 64 + m * 16 + rb;
      const int gc = bcol + wc * (BN / 2) + n * 16 + cc;
#pragma unroll
      for (int q = 0; q < 4; ++q) {
        const size_t idx = (size_t)(gr + q) * N + gc;
        const float v = acc[m][n][q];
        if constexpr (EPI == 0) {
          Cf[idx] = v;
        } else if constexpr (EPI == 1) {
          Cf[idx] = resid[idx] + v + bias[gc];
        } else {
          const float u = v + bias[gc];
          Ch[idx] = f2h(0.5f * u * (1.0f + erff(u * 0.70710678118654752f)));
        }
      }
    }
  }
}

// ---------------------------------------------------------------------------
// LayerNorm (fp32 stats) -> fp16 out. One block per row.
// ---------------------------------------------------------------------------
__global__ __launch_bounds__(256) void ln_f16(
    const float* __restrict__ x, const float* __restrict__ g,
    const float* __restrict__ b, _Float16* __restrict__ out)
{
  const int row = blockIdx.x;
  const int t = threadIdx.x;
  const size_t base = (size_t)row * D + t * 4;
  const float4 v = *(const float4*)(x + base);
  float s = v.x + v.y + v.z + v.w;
  float q = v.x * v.x + v.y * v.y + v.z * v.z + v.w * v.w;
#pragma unroll
  for (int off = 32; off > 0; off >>= 1) {
    s += __shfl_xor(s, off);
    q += __shfl_xor(q, off);
  }
  __shared__ float rs[4], rq[4];
  const int wid = t >> 6, lane = t & 63;
  if (lane == 0) { rs[wid] = s; rq[wid] = q; }
  __syncthreads();
  s = rs[0] + rs[1] + rs[2] + rs[3];
  q = rq[0] + rq[1] + rq[2] + rq[3];
  const float mean = s * (1.0f / D);
  const float var = q * (1.0f / D) - mean * mean;
  const float rstd = rsqrtf(var + 1e-5f);
  const float4 gg = *(const float4*)(g + t * 4);
  const float4 bb = *(const float4*)(b + t * 4);
  f16x4 o;
  o[0] = f2h((v.x - mean) * rstd * gg.x + bb.x);
  o[1] = f2h((v.y - mean) * rstd * gg.y + bb.y);
  o[2] = f2h((v.z - mean) * rstd * gg.z + bb.z);
  o[3] = f2h((v.w - mean) * rstd * gg.w + bb.w);
  *(f16x4*)(out + base) = o;
}

// ---------------------------------------------------------------------------
// Diagonal complex scan, chunked. |lambda| < 0.5 -> 64-step warm-up is exact
// to fp32 (0.5^64 ~ 5e-20). Thread = k, block = (chunk, batch).
// ---------------------------------------------------------------------------
__global__ __launch_bounds__(64) void scan_k(
    const float* __restrict__ beta, const float* __restrict__ state,
    const float* __restrict__ alpha, const float* __restrict__ omega,
    _Float16* __restrict__ c_cat, float* __restrict__ fs)
{
  const int k = threadIdx.x;
  const int chunk = blockIdx.x;   // 0..63 (64 steps each)
  const int b = blockIdx.y;       // 0..3
  const float a = alpha[k];
  const float mag = 1.0f / (1.0f + expf(-a));
  const float om = omega[k];
  const float lr = mag * cosf(om);
  const float li = mag * sinf(om);
  const int t0 = chunk * 64;
  float cr, ci;
  int t;
  if (chunk == 0) {
    cr = state[(b * 64 + k) * 2 + 0];
    ci = state[(b * 64 + k) * 2 + 1];
    t = 0;
  } else {
    cr = 0.0f; ci = 0.0f;
    t = t0 - 64;                  // warm-up window
  }
  for (; t < t0 + 64; ++t) {
    const float* bp = beta + ((size_t)(b * TSEQ + t) << 7);
    const float br = bp[k];
    const float bi = bp[64 + k];
    const float ncr = lr * cr - li * ci + br;
    const float nci = lr * ci + li * cr + bi;
    cr = ncr; ci = nci;
    if (t >= t0) {
      _Float16* cp = c_cat + ((size_t)(b * TSEQ + t) << 7);
      cp[k] = f2h(cr);
      cp[64 + k] = f2h(ci);
    }
  }
  if (chunk == 63) {
    fs[(b * 64 + k) * 2 + 0] = cr;
    fs[(b * 64 + k) * 2 + 1] = ci;
  }
}

// ---------------------------------------------------------------------------
// transpose + fp32->fp16:  dst[C][R] = src[R][C]
// ---------------------------------------------------------------------------
__global__ void tr_cvt(const float* __restrict__ src, _Float16* __restrict__ dst,
                       int R, int C)
{
  __shared__ float tile[32][33];
  const int bx = blockIdx.x * 32;  // col base in src
  const int by = blockIdx.y * 32;  // row base in src
  const int tx = threadIdx.x, ty = threadIdx.y;
#pragma unroll
  for (int i = 0; i < 32; i += 8)
    tile[ty + i][tx] = src[(size_t)(by + ty + i) * C + bx + tx];
  __syncthreads();
#pragma unroll
  for (int i = 0; i < 32; i += 8)
    dst[(size_t)(bx + ty + i) * R + by + tx] = f2h(tile[tx][ty + i]);
}

// Ecat[128][1024] = [eigvec_real ; -eigvec_imag]  (fp16)
__global__ void build_Ecat(const float* __restrict__ er, const float* __restrict__ ei,
                           _Float16* __restrict__ E)
{
  const int i = blockIdx.x * 256 + threadIdx.x;  // 0..131071
  const float v = (i < 65536) ? er[i] : -ei[i - 65536];
  E[i] = f2h(v);
}

// G[128][1024] = [R^T @ er ; -(R^T @ ei)],  R = I + eps*M  => R^T[j][k] = d_jk + eps*M[k][j]
__global__ void build_G(const float* __restrict__ er, const float* __restrict__ ei,
                        const float* __restrict__ Mm, const float* __restrict__ epsp,
                        float* __restrict__ G)
{
  const int j = blockIdx.y;                       // 0..127
  const int d = blockIdx.x * 256 + threadIdx.x;   // 0..1023
  const float* e = (j < 64) ? er : ei;
  const int jj = j & 63;
  const float eps = epsp[0];
  float acc = 0.0f;
  for (int k = 0; k < 64; ++k)
    acc += Mm[k * 64 + jj] * e[(size_t)k * D + d];
  const float v = e[(size_t)jj * D + d] + eps * acc;
  G[(size_t)j * D + d] = (j < 64) ? v : -v;
}

// WhoT[1024][128] (fp16) = (G @ out_w)^T  -- folds eigen readout + out_w into one 128xD matrix
__global__ void build_WhoT(const float* __restrict__ G, const float* __restrict__ ow,
                           _Float16* __restrict__ WhoT)
{
  const int j = blockIdx.y;                       // 0..127
  const int d = blockIdx.x * 256 + threadIdx.x;   // 0..1023
  float acc = 0.0f;
  for (int k = 0; k < D; ++k)
    acc += G[(size_t)j * D + k] * ow[(size_t)k * D + d];
  WhoT[(size_t)d * 128 + j] = f2h(acc);
}

// ---------------------------------------------------------------------------
extern "C" void kernel_launch(void* const* d_in, const int* in_sizes, int n_in,
                              void* d_out, int out_size, void* d_ws, size_t ws_size,
                              hipStream_t stream) {
  const float* x     = (const float*)d_in[0];
  const float* state = (const float*)d_in[1];
  const float* er    = (const float*)d_in[2];
  const float* ei    = (const float*)d_in[3];
  const float* alpha = (const float*)d_in[4];
  const float* omega = (const float*)d_in[5];
  const float* epsv  = (const float*)d_in[6];
  const float* Mm    = (const float*)d_in[7];
  const float* out_w = (const float*)d_in[8];
  const float* out_b = (const float*)d_in[9];
  const float* w1    = (const float*)d_in[10];
  const float* b1    = (const float*)d_in[11];
  const float* w2    = (const float*)d_in[12];
  const float* b2    = (const float*)d_in[13];
  const float* g1    = (const float*)d_in[14];
  const float* be1   = (const float*)d_in[15];
  const float* g2    = (const float*)d_in[16];
  const float* be2   = (const float*)d_in[17];

  float* out = (float*)d_out;
  float* fs  = out + (size_t)BT_ROWS * D;   // final_state after the (B,T,D) block
  float* y   = out;                          // y lives in d_out (overwritten in-place at the end)

  // ---- workspace layout: ~85 MB total (validated in Round 3) ----
  char* w = (char*)d_ws;
  _Float16* act  = (_Float16*)(w);                 // 32 MB  (CHUNK x 4096 fp16) -- stage 3
  float*    beta = (float*)   (w);                 //  8 MB  (aliases act; dead before stage 3)
  _Float16* ccat = (_Float16*)(w + 8388608u);      //  4 MB  (aliases act; dead before stage 3)
  _Float16* xnyn = (_Float16*)(w + 33554432u);     // 32 MB  (xn stage 1, yn stages 2-3)
  _Float16* w1T  = (_Float16*)(w + 67108864u);     //  8 MB
  _Float16* w2T  = (_Float16*)(w + 75497472u);     //  8 MB
  float*    G    = (float*)   (w + 83886080u);     // 512 KB
  _Float16* WhoT = (_Float16*)(w + 84410368u);     // 256 KB
  _Float16* Ecat = (_Float16*)(w + 84672512u);     // 256 KB   (end ~84.9 MB)

  // stage 0: small precomputes + weight transposes (independent)
  build_Ecat<<<512, 256, 0, stream>>>(er, ei, Ecat);
  build_G<<<dim3(4, 128), 256, 0, stream>>>(er, ei, Mm, epsv, G);
  build_WhoT<<<dim3(4, 128), 256, 0, stream>>>(G, out_w, WhoT);
  tr_cvt<<<dim3(128, 32), dim3(32, 8), 0, stream>>>(w1, w1T, 1024, 4096);
  tr_cvt<<<dim3(32, 128), dim3(32, 8), 0, stream>>>(w2, w2T, 4096, 1024);

  // stage 1: LN1 -> beta -> scan
  ln_f16<<<BT_ROWS, 256, 0, stream>>>(x, g1, be1, xnyn);
  gemm_bt<0, 2><<<dim3(2, 128), 256, 0, stream>>>(xnyn, Ecat, 128, 1024, beta, nullptr, nullptr, nullptr);
  scan_k<<<dim3(64, 4), 64, 0, stream>>>(beta, state, alpha, omega, ccat, fs);

  // stage 2: y = x + ccat @ Who + out_b  (into d_out); LN2 -> yn
  gemm_bt<1, 4><<<dim3(8, 128), 256, 0, stream>>>(ccat, WhoT, 1024, 128, y, nullptr, out_b, x);
  ln_f16<<<BT_ROWS, 256, 0, stream>>>(y, g2, be2, xnyn);

  // stage 3: MLP, row-chunked x4; final residual in-place on d_out
  for (int c = 0; c < BT_ROWS / CHUNK; ++c) {
    const size_t ro = (size_t)c * CHUNK;
    gemm_bt<2, 4><<<dim3(32, CHUNK / 128), 256, 0, stream>>>(
        xnyn + ro * D, w1T, 4096, 1024, nullptr, act, b1, nullptr);
    gemm_bt<1, 2><<<dim3(16, CHUNK / 128), 256, 0, stream>>>(
        act, w2T, 1024, 4096, out + ro * D, nullptr, b2, y + ro * D);
  }
}

// Round 5
// 689.818 us; speedup vs baseline: 1.3867x; 1.0305x over previous
//
#include <hip/hip_runtime.h>
#include <hip/hip_bf16.h>
#include <math.h>

// TENLayer: LN1 -> eigen-projection -> diagonal complex scan -> folded readout GEMM
//           -> +residual -> LN2 -> MLP(gelu exact) -> +residual.  fp16 MFMA GEMMs.
//
// Round 5: MLP-up GEMM (the dominant cost) ported to a 256x256-tile 8-wave
// 4-phase/K-tile schedule (T3+T4 counted vmcnt, T5 setprio, T2 swizzle kept).
// Other GEMMs stay on the proven 2-phase 128xBN kernel.

#define D 1024
#define TSEQ 4096
#define BT_ROWS 16384
#define CHUNK 4096            // MLP row-chunk (4 chunks)

typedef __attribute__((ext_vector_type(8))) _Float16 f16x8;
typedef __attribute__((ext_vector_type(4))) _Float16 f16x4;
typedef __attribute__((ext_vector_type(4))) float f32x4;

__device__ inline _Float16 f2h(float f) { return (_Float16)f; }

#define GLL16(g, l)                                                              \
  __builtin_amdgcn_global_load_lds(                                              \
      (const __attribute__((address_space(1))) void*)(g),                        \
      (__attribute__((address_space(3))) void*)(l), 16, 0, 0)

#define WAITVM(n)  asm volatile("s_waitcnt vmcnt(" #n ")" ::: "memory")
#define WAITLGKM() asm volatile("s_waitcnt lgkmcnt(0)" ::: "memory")

// ---------------------------------------------------------------------------
// 256x256-tile GEMM, 512 threads (8 waves, 2Mx4N), BK=64, 2 LDS buffers
// (128 KiB dynamic). Per K-tile: 4 phases, each {stage-1-half | ds_reads |
// lgkm | setprio MFMA setprio | barrier}; counted vmcnt(2) at tile boundary.
// Per-wave output 128x64 = acc[8][4] f32x4. Swizzle: phys_kblk = kblk^(row&7),
// staged via pre-swizzled global source (both-sides, proven R4: 0 conflicts).
// EPI: 2 = gelu(acc+bias) -> fp16.  Requires Kd multiple of 64, Kd >= 128.
// ---------------------------------------------------------------------------
template <int EPI>
__global__ __launch_bounds__(512, 2) void gemm256(
    const _Float16* __restrict__ A, const _Float16* __restrict__ Bt,
    int N, int Kd,
    float* __restrict__ Cf, _Float16* __restrict__ Ch,
    const float* __restrict__ bias, const float* __restrict__ resid)
{
  extern __shared__ __align__(16) _Float16 ldsraw[];   // 2 bufs x 32768 halfs
  const int t = threadIdx.x;
  const int wid = t >> 6, lane = t & 63;
  const int wr = wid >> 2, wc = wid & 3;               // 2 x 4 wave grid
  const int brow = blockIdx.y << 8, bcol = blockIdx.x << 8;

  f32x4 acc[8][4] = {};

  // staging map: thread t -> row srow (0..63) within a 64-row call group,
  // source k-block pre-swizzled so linear LDS slot (t&7) holds kblk^(row&7).
  const int srow = t >> 3;
  const int skb8 = ((t & 7) ^ (srow & 7)) << 3;        // halfs
  const _Float16* gA = A + (size_t)(brow + srow) * Kd + skb8;
  const _Float16* gB = Bt + (size_t)(bcol + srow) * Kd + skb8;
  const int ldst = t * 8;                               // halfs, linear

  // stage one half-tile (128 rows = 2 x 64-row gll groups). obase: 0=A, 16384=B.
  auto stageH = [&](int buf, int obase, int h, int kt) {
    const _Float16* gp = obase ? gB : gA;
    _Float16* dst = ldsraw + buf * 32768 + obase + h * 8192 + ldst;
    GLL16(gp + (size_t)(h * 128) * Kd + (size_t)kt * 64, dst);
    GLL16(gp + (size_t)(h * 128 + 64) * Kd + (size_t)kt * 64, dst + 4096);
  };

  const int rr = lane & 15, g4 = lane >> 4;
  auto rdA = [&](int buf, int m, int kk) -> f16x8 {     // m 0..7
    const int row = wr * 128 + m * 16 + rr;
    const int kblk = kk * 4 + g4;
    return *(const f16x8*)&ldsraw[buf * 32768 + row * 64 + ((kblk ^ (row & 7)) << 3)];
  };
  auto rdB = [&](int buf, int n, int kk) -> f16x8 {     // n 0..3
    const int row = wc * 64 + n * 16 + rr;
    const int kblk = kk * 4 + g4;
    return *(const f16x8*)&ldsraw[buf * 32768 + 16384 + row * 64 + ((kblk ^ (row & 7)) << 3)];
  };

  const int nt = Kd >> 6;                               // K-tiles (>= 2)

  // prologue: tile0 fully + A-half0(tile1); wait all but the last half-tile
  stageH(0, 0, 0, 0); stageH(0, 0, 1, 0);
  stageH(0, 16384, 0, 0); stageH(0, 16384, 1, 0);
  stageH(1, 0, 0, 1);
  WAITVM(2);
  __builtin_amdgcn_s_barrier();

  f16x8 af[4][2], bf0[2][2], bf1[2][2];

  for (int j = 0; j < nt; ++j) {
    const int c = j & 1;

    // ---- P1: stage A1(j+1) | read af(mh0) + bf(nh0) | MFMA q(0,0)
    if (j + 1 < nt) stageH(c ^ 1, 0, 1, j + 1);
#pragma unroll
    for (int m = 0; m < 4; ++m)
#pragma unroll
      for (int kk = 0; kk < 2; ++kk) af[m][kk] = rdA(c, m, kk);
#pragma unroll
    for (int n = 0; n < 2; ++n)
#pragma unroll
      for (int kk = 0; kk < 2; ++kk) bf0[n][kk] = rdB(c, n, kk);
    WAITLGKM();
    __builtin_amdgcn_s_setprio(1);
#pragma unroll
    for (int m = 0; m < 4; ++m)
#pragma unroll
      for (int n = 0; n < 2; ++n)
#pragma unroll
        for (int kk = 0; kk < 2; ++kk)
          acc[m][n] = __builtin_amdgcn_mfma_f32_16x16x32_f16(af[m][kk], bf0[n][kk], acc[m][n], 0, 0, 0);
    __builtin_amdgcn_s_setprio(0);
    __builtin_amdgcn_s_barrier();

    // ---- P2: stage B0(j+1) | read bf(nh1) | MFMA q(0,1)
    if (j + 1 < nt) stageH(c ^ 1, 16384, 0, j + 1);
#pragma unroll
    for (int n = 0; n < 2; ++n)
#pragma unroll
      for (int kk = 0; kk < 2; ++kk) bf1[n][kk] = rdB(c, n + 2, kk);
    WAITLGKM();
    __builtin_amdgcn_s_setprio(1);
#pragma unroll
    for (int m = 0; m < 4; ++m)
#pragma unroll
      for (int n = 0; n < 2; ++n)
#pragma unroll
        for (int kk = 0; kk < 2; ++kk)
          acc[m][n + 2] = __builtin_amdgcn_mfma_f32_16x16x32_f16(af[m][kk], bf1[n][kk], acc[m][n + 2], 0, 0, 0);
    __builtin_amdgcn_s_setprio(0);
    __builtin_amdgcn_s_barrier();

    // ---- P3: stage B1(j+1) | read af(mh1) | MFMA q(1,0)
    if (j + 1 < nt) stageH(c ^ 1, 16384, 1, j + 1);
#pragma unroll
    for (int m = 0; m < 4; ++m)
#pragma unroll
      for (int kk = 0; kk < 2; ++kk) af[m][kk] = rdA(c, m + 4, kk);
    WAITLGKM();                 // also releases buf c: all its reads are done
    __builtin_amdgcn_s_setprio(1);
#pragma unroll
    for (int m = 0; m < 4; ++m)
#pragma unroll
      for (int n = 0; n < 2; ++n)
#pragma unroll
        for (int kk = 0; kk < 2; ++kk)
          acc[m + 4][n] = __builtin_amdgcn_mfma_f32_16x16x32_f16(af[m][kk], bf0[n][kk], acc[m + 4][n], 0, 0, 0);
    __builtin_amdgcn_s_setprio(0);
    __builtin_amdgcn_s_barrier();

    // ---- P4: stage A0(j+2) into buf c (released at P3) | MFMA q(1,1)
    if (j + 2 < nt) stageH(c, 0, 0, j + 2);
    __builtin_amdgcn_s_setprio(1);
#pragma unroll
    for (int m = 0; m < 4; ++m)
#pragma unroll
      for (int n = 0; n < 2; ++n)
#pragma unroll
        for (int kk = 0; kk < 2; ++kk)
          acc[m + 4][n + 2] = __builtin_amdgcn_mfma_f32_16x16x32_f16(af[m][kk], bf1[n][kk], acc[m + 4][n + 2], 0, 0, 0);
    __builtin_amdgcn_s_setprio(0);

    if (j + 1 < nt) {
      if (j + 2 < nt) { WAITVM(2); }   // keep A0(j+2) in flight across barrier
      else            { WAITVM(0); }   // tail: drain
      __builtin_amdgcn_s_barrier();
    }
  }

  // C/D layout: col = lane&15, row = (lane>>4)*4 + reg
  const int cc = lane & 15;
  const int rb = (lane >> 4) << 2;
#pragma unroll
  for (int m = 0; m < 8; ++m) {
#pragma unroll
    for (int n = 0; n < 4; ++n) {
      const int gr = brow + wr * 128 + m * 16 + rb;
      const int gc = bcol + wc * 64 + n * 16 + cc;
#pragma unroll
      for (int q = 0; q < 4; ++q) {
        const size_t idx = (size_t)(gr + q) * N + gc;
        const float v = acc[m][n][q];
        if constexpr (EPI == 0) {
          Cf[idx] = v;
        } else if constexpr (EPI == 1) {
          Cf[idx] = resid[idx] + v + bias[gc];
        } else {
          const float u = v + bias[gc];
          Ch[idx] = f2h(0.5f * u * (1.0f + erff(u * 0.70710678118654752f)));
        }
      }
    }
  }
}

// ---------------------------------------------------------------------------
// 2-phase 128xBN GEMM (proven R4) — used for gemm2 / readout / beta.
// ---------------------------------------------------------------------------
template <int EPI, int NFRAG>
__global__ __launch_bounds__(256) void gemm_bt(
    const _Float16* __restrict__ A, const _Float16* __restrict__ Bt,
    int N, int Kd,
    float* __restrict__ Cf, _Float16* __restrict__ Ch,
    const float* __restrict__ bias, const float* __restrict__ resid)
{
  constexpr int BN = NFRAG * 32;
  constexpr int BCALLS = BN / 32;
  constexpr int ASZ = 128 * 64;
  constexpr int BSZ = BN * 64;
  __shared__ __align__(16) _Float16 lds[2][ASZ + BSZ];

  const int t = threadIdx.x;
  const int wid = t >> 6, lane = t & 63;
  const int brow = blockIdx.y << 7;
  const int bcol = blockIdx.x * BN;
  const int wr = wid >> 1, wc = wid & 1;

  f32x4 acc[4][NFRAG] = {};

  const int srow = t >> 3;
  const int skb = (((t & 7) ^ (srow & 7)) << 3);
  const _Float16* gA = A + (size_t)(brow + srow) * Kd + skb;
  const _Float16* gB = Bt + (size_t)(bcol + srow) * Kd + skb;

  const int rr = lane & 15, g = lane >> 4;

  auto stage = [&](int buf, int k0) {
    _Float16* dst = &lds[buf][0];
#pragma unroll
    for (int i = 0; i < 4; ++i)
      GLL16(gA + (size_t)(i * 32) * Kd + k0, dst + i * 2048 + t * 8);
#pragma unroll
    for (int i = 0; i < BCALLS; ++i)
      GLL16(gB + (size_t)(i * 32) * Kd + k0, dst + ASZ + i * 2048 + t * 8);
  };

  const int nsteps = Kd >> 6;
  stage(0, 0);
  int cur = 0;
  for (int s = 0; s < nsteps; ++s) {
    if (s + 1 < nsteps) {
      stage(cur ^ 1, (s + 1) << 6);
      if constexpr (NFRAG == 4) { WAITVM(8); }
      else                      { WAITVM(6); }
    } else {
      WAITVM(0);
    }
    __builtin_amdgcn_s_barrier();

    const _Float16* la = &lds[cur][0];
    const _Float16* lb = la + ASZ;
#pragma unroll
    for (int kk = 0; kk < 2; ++kk) {
      f16x8 af[4], bfr[NFRAG];
#pragma unroll
      for (int m = 0; m < 4; ++m) {
        const int row = wr * 64 + m * 16 + rr;
        af[m] = *(const f16x8*)&la[row * 64 + (((g + 4 * kk) ^ (row & 7)) << 3)];
      }
#pragma unroll
      for (int n = 0; n < NFRAG; ++n) {
        const int row = wc * (BN / 2) + n * 16 + rr;
        bfr[n] = *(const f16x8*)&lb[row * 64 + (((g + 4 * kk) ^ (row & 7)) << 3)];
      }
#pragma unroll
      for (int m = 0; m < 4; ++m)
#pragma unroll
        for (int n = 0; n < NFRAG; ++n)
          acc[m][n] = __builtin_amdgcn_mfma_f32_16x16x32_f16(af[m], bfr[n], acc[m][n], 0, 0, 0);
    }
    WAITLGKM();
    __builtin_amdgcn_s_barrier();
    cur ^= 1;
  }

  const int cc = lane & 15;
  const int rb = (lane >> 4) << 2;
#pragma unroll
  for (int m = 0; m < 4; ++m) {
#pragma unroll
    for (int n = 0; n < NFRAG; ++n) {
      const int gr = brow + wr * 64 + m * 16 + rb;
      const int gc = bcol + wc * (BN / 2) + n * 16 + cc;
#pragma unroll
      for (int q = 0; q < 4; ++q) {
        const size_t idx = (size_t)(gr + q) * N + gc;
        const float v = acc[m][n][q];
        if constexpr (EPI == 0) {
          Cf[idx] = v;
        } else if constexpr (EPI == 1) {
          Cf[idx] = resid[idx] + v + bias[gc];
        } else {
          const float u = v + bias[gc];
          Ch[idx] = f2h(0.5f * u * (1.0f + erff(u * 0.70710678118654752f)));
        }
      }
    }
  }
}

// ---------------------------------------------------------------------------
// LayerNorm (fp32 stats) -> fp16 out. One block per row.
// ---------------------------------------------------------------------------
__global__ __launch_bounds__(256) void ln_f16(
    const float* __restrict__ x, const float* __restrict__ g,
    const float* __restrict__ b, _Float16* __restrict__ out)
{
  const int row = blockIdx.x;
  const int t = threadIdx.x;
  const size_t base = (size_t)row * D + t * 4;
  const float4 v = *(const float4*)(x + base);
  float s = v.x + v.y + v.z + v.w;
  float q = v.x * v.x + v.y * v.y + v.z * v.z + v.w * v.w;
#pragma unroll
  for (int off = 32; off > 0; off >>= 1) {
    s += __shfl_xor(s, off);
    q += __shfl_xor(q, off);
  }
  __shared__ float rs[4], rq[4];
  const int wid = t >> 6, lane = t & 63;
  if (lane == 0) { rs[wid] = s; rq[wid] = q; }
  __syncthreads();
  s = rs[0] + rs[1] + rs[2] + rs[3];
  q = rq[0] + rq[1] + rq[2] + rq[3];
  const float mean = s * (1.0f / D);
  const float var = q * (1.0f / D) - mean * mean;
  const float rstd = rsqrtf(var + 1e-5f);
  const float4 gg = *(const float4*)(g + t * 4);
  const float4 bb = *(const float4*)(b + t * 4);
  f16x4 o;
  o[0] = f2h((v.x - mean) * rstd * gg.x + bb.x);
  o[1] = f2h((v.y - mean) * rstd * gg.y + bb.y);
  o[2] = f2h((v.z - mean) * rstd * gg.z + bb.z);
  o[3] = f2h((v.w - mean) * rstd * gg.w + bb.w);
  *(f16x4*)(out + base) = o;
}

// ---------------------------------------------------------------------------
// Diagonal complex scan, chunked (64-step warm-up, exact to fp32 since |lam|<0.5).
// ---------------------------------------------------------------------------
__global__ __launch_bounds__(64) void scan_k(
    const float* __restrict__ beta, const float* __restrict__ state,
    const float* __restrict__ alpha, const float* __restrict__ omega,
    _Float16* __restrict__ c_cat, float* __restrict__ fs)
{
  const int k = threadIdx.x;
  const int chunk = blockIdx.x;
  const int b = blockIdx.y;
  const float a = alpha[k];
  const float mag = 1.0f / (1.0f + expf(-a));
  const float om = omega[k];
  const float lr = mag * cosf(om);
  const float li = mag * sinf(om);
  const int t0 = chunk * 64;
  float cr, ci;
  int t;
  if (chunk == 0) {
    cr = state[(b * 64 + k) * 2 + 0];
    ci = state[(b * 64 + k) * 2 + 1];
    t = 0;
  } else {
    cr = 0.0f; ci = 0.0f;
    t = t0 - 64;
  }
  for (; t < t0 + 64; ++t) {
    const float* bp = beta + ((size_t)(b * TSEQ + t) << 7);
    const float br = bp[k];
    const float bi = bp[64 + k];
    const float ncr = lr * cr - li * ci + br;
    const float nci = lr * ci + li * cr + bi;
    cr = ncr; ci = nci;
    if (t >= t0) {
      _Float16* cp = c_cat + ((size_t)(b * TSEQ + t) << 7);
      cp[k] = f2h(cr);
      cp[64 + k] = f2h(ci);
    }
  }
  if (chunk == 63) {
    fs[(b * 64 + k) * 2 + 0] = cr;
    fs[(b * 64 + k) * 2 + 1] = ci;
  }
}

// ---------------------------------------------------------------------------
__global__ void tr_cvt(const float* __restrict__ src, _Float16* __restrict__ dst,
                       int R, int C)
{
  __shared__ float tile[32][33];
  const int bx = blockIdx.x * 32;
  const int by = blockIdx.y * 32;
  const int tx = threadIdx.x, ty = threadIdx.y;
#pragma unroll
  for (int i = 0; i < 32; i += 8)
    tile[ty + i][tx] = src[(size_t)(by + ty + i) * C + bx + tx];
  __syncthreads();
#pragma unroll
  for (int i = 0; i < 32; i += 8)
    dst[(size_t)(bx + ty + i) * R + by + tx] = f2h(tile[tx][ty + i]);
}

__global__ void build_Ecat(const float* __restrict__ er, const float* __restrict__ ei,
                           _Float16* __restrict__ E)
{
  const int i = blockIdx.x * 256 + threadIdx.x;
  const float v = (i < 65536) ? er[i] : -ei[i - 65536];
  E[i] = f2h(v);
}

__global__ void build_G(const float* __restrict__ er, const float* __restrict__ ei,
                        const float* __restrict__ Mm, const float* __restrict__ epsp,
                        float* __restrict__ G)
{
  const int j = blockIdx.y;
  const int d = blockIdx.x * 256 + threadIdx.x;
  const float* e = (j < 64) ? er : ei;
  const int jj = j & 63;
  const float eps = epsp[0];
  float acc = 0.0f;
  for (int k = 0; k < 64; ++k)
    acc += Mm[k * 64 + jj] * e[(size_t)k * D + d];
  const float v = e[(size_t)jj * D + d] + eps * acc;
  G[(size_t)j * D + d] = (j < 64) ? v : -v;
}

__global__ void build_WhoT(const float* __restrict__ G, const float* __restrict__ ow,
                           _Float16* __restrict__ WhoT)
{
  const int j = blockIdx.y;
  const int d = blockIdx.x * 256 + threadIdx.x;
  float acc = 0.0f;
  for (int k = 0; k < D; ++k)
    acc += G[(size_t)j * D + k] * ow[(size_t)k * D + d];
  WhoT[(size_t)d * 128 + j] = f2h(acc);
}

// ---------------------------------------------------------------------------
extern "C" void kernel_launch(void* const* d_in, const int* in_sizes, int n_in,
                              void* d_out, int out_size, void* d_ws, size_t ws_size,
                              hipStream_t stream) {
  const float* x     = (const float*)d_in[0];
  const float* state = (const float*)d_in[1];
  const float* er    = (const float*)d_in[2];
  const float* ei    = (const float*)d_in[3];
  const float* alpha = (const float*)d_in[4];
  const float* omega = (const float*)d_in[5];
  const float* epsv  = (const float*)d_in[6];
  const float* Mm    = (const float*)d_in[7];
  const float* out_w = (const float*)d_in[8];
  const float* out_b = (const float*)d_in[9];
  const float* w1    = (const float*)d_in[10];
  const float* b1    = (const float*)d_in[11];
  const float* w2    = (const float*)d_in[12];
  const float* b2    = (const float*)d_in[13];
  const float* g1    = (const float*)d_in[14];
  const float* be1   = (const float*)d_in[15];
  const float* g2    = (const float*)d_in[16];
  const float* be2   = (const float*)d_in[17];

  float* out = (float*)d_out;
  float* fs  = out + (size_t)BT_ROWS * D;
  float* y   = out;

  // ---- workspace layout: ~85 MB (validated R3/R4) ----
  char* w = (char*)d_ws;
  _Float16* act  = (_Float16*)(w);                 // 32 MB  (stage 3)
  float*    beta = (float*)   (w);                 //  8 MB  (aliases act)
  _Float16* ccat = (_Float16*)(w + 8388608u);      //  4 MB  (aliases act)
  _Float16* xnyn = (_Float16*)(w + 33554432u);     // 32 MB
  _Float16* w1T  = (_Float16*)(w + 67108864u);     //  8 MB
  _Float16* w2T  = (_Float16*)(w + 75497472u);     //  8 MB
  float*    G    = (float*)   (w + 83886080u);     // 512 KB
  _Float16* WhoT = (_Float16*)(w + 84410368u);     // 256 KB
  _Float16* Ecat = (_Float16*)(w + 84672512u);     // 256 KB

  // stage 0: small precomputes + weight transposes
  build_Ecat<<<512, 256, 0, stream>>>(er, ei, Ecat);
  build_G<<<dim3(4, 128), 256, 0, stream>>>(er, ei, Mm, epsv, G);
  build_WhoT<<<dim3(4, 128), 256, 0, stream>>>(G, out_w, WhoT);
  tr_cvt<<<dim3(128, 32), dim3(32, 8), 0, stream>>>(w1, w1T, 1024, 4096);
  tr_cvt<<<dim3(32, 128), dim3(32, 8), 0, stream>>>(w2, w2T, 4096, 1024);

  // stage 1: LN1 -> beta -> scan
  ln_f16<<<BT_ROWS, 256, 0, stream>>>(x, g1, be1, xnyn);
  gemm_bt<0, 2><<<dim3(2, 128), 256, 0, stream>>>(xnyn, Ecat, 128, 1024, beta, nullptr, nullptr, nullptr);
  scan_k<<<dim3(64, 4), 64, 0, stream>>>(beta, state, alpha, omega, ccat, fs);

  // stage 2: y = x + ccat @ Who + out_b (into d_out); LN2 -> yn
  gemm_bt<1, 4><<<dim3(8, 128), 256, 0, stream>>>(ccat, WhoT, 1024, 128, y, nullptr, out_b, x);
  ln_f16<<<BT_ROWS, 256, 0, stream>>>(y, g2, be2, xnyn);

  // stage 3: MLP, row-chunked x4; final residual in-place on d_out
  for (int c = 0; c < BT_ROWS / CHUNK; ++c) {
    const size_t ro = (size_t)c * CHUNK;
    gemm256<2><<<dim3(16, CHUNK / 256), 512, 131072, stream>>>(
        xnyn + ro * D, w1T, 4096, 1024, nullptr, act, b1, nullptr);
    gemm_bt<1, 2><<<dim3(16, CHUNK / 128), 256, 0, stream>>>(
        act, w2T, 1024, 4096, out + ro * D, nullptr, b2, y + ro * D);
  }
}